// Round 12
// baseline (1122.188 us; speedup 1.0000x reference)
//
#include <hip/hip_runtime.h>
#include <hip/hip_bf16.h>
#include <math.h>

#define BB 8
#define NN 4096
#define NIN 64
#define NOUTF 128
#define KNB 32
#define MM 1024
#define DIM 68
#define CAP 320

typedef float f32x2 __attribute__((ext_vector_type(2)));

// Separate single-instruction VOP3P asm helpers: compiler interleaves
// independent j-iterations between them (critical at 1 wave/SIMD).
__device__ __forceinline__ f32x2 pk_add(f32x2 a, f32x2 b)
{
    f32x2 d;
    asm("v_pk_add_f32 %0, %1, %2" : "=v"(d) : "v"(a), "v"(b));
    return d;
}
__device__ __forceinline__ f32x2 pk_mul(f32x2 a, f32x2 b)
{
    f32x2 d;
    asm("v_pk_mul_f32 %0, %1, %2" : "=v"(d) : "v"(a), "v"(b));
    return d;
}

__device__ __forceinline__ f32x2 pkmax(f32x2 a, f32x2 b)
{
    f32x2 r; r.x = fmaxf(a.x, b.x); r.y = fmaxf(a.y, b.y); return r;
}

template <int CTRL>
__device__ __forceinline__ float dppmax(float v)
{
    int m = __builtin_amdgcn_update_dpp(__float_as_int(v), __float_as_int(v),
                                        CTRL, 0xF, 0xF, false);
    return fmaxf(v, __int_as_float(m));
}

// ---------------------------------------------------------------------------
// Kernel 1: farthest point sampling. R11 structure (256 thr = 4 waves,
// 16 pts/thread, max-only scan, DPP wave-max + ballot, 1 barrier, LDS-buffered
// emit) with ONE change: winner coords are SPECULATIVELY gathered from SoA
// LDS (posLx/y/z) by every lane for its own candidate right after local
// argmax recovery — the gather's latency hides under the DPP chain + ballot,
// and the coords ride through the reduction slot. The post-merge dependent
// posL read (~120 cy on the critical path) is gone.
// Exact-match: contract off, (dx²+dy²)+dz² order, first-occurrence argmax.
// ---------------------------------------------------------------------------
__global__ __launch_bounds__(256) void fps_kernel(
    const float* __restrict__ pos,
    int* __restrict__ idx_ws,
    float* __restrict__ out_pos_s, float* __restrict__ out_idx)
{
#pragma clang fp contract(off)
    __shared__ float  posLx[NN];     // 16 KiB each: SoA for conflict-light
    __shared__ float  posLy[NN];     //   random gather (b32: ~2 lanes/bank)
    __shared__ float  posLz[NN];
    __shared__ float4 slotP[2][4];   // {x,y,z,val} per wave, double-buffered
    __shared__ int    slotI[2][4];   // winner index per wave
    __shared__ float4 emitP[MM];     // 16 KiB sample coords
    __shared__ int    emitI[MM];     // 4 KiB sample indices

    const int b    = blockIdx.x;
    const int tid  = threadIdx.x;
    const int wv   = tid >> 6;
    const int lane = tid & 63;
    const float* pb = pos + (size_t)b * NN * 3;

    f32x2 X[8], Y[8], Z[8], D[8];
#pragma unroll
    for (int j = 0; j < 8; ++j) {
        int pA = tid * 16 + 2 * j;
        X[j].x = pb[pA * 3 + 0]; X[j].y = pb[pA * 3 + 3];
        Y[j].x = pb[pA * 3 + 1]; Y[j].y = pb[pA * 3 + 4];
        Z[j].x = pb[pA * 3 + 2]; Z[j].y = pb[pA * 3 + 5];
        D[j].x = INFINITY;       D[j].y = INFINITY;
    }
    // SoA init, coalesced: consecutive threads -> consecutive floats
#pragma unroll
    for (int j = 0; j < 16; ++j) {
        int p2 = tid + 256 * j;
        posLx[p2] = pb[p2 * 3 + 0];
        posLy[p2] = pb[p2 * 3 + 1];
        posLz[p2] = pb[p2 * 3 + 2];
    }
    __syncthreads();

    int   last = 0;
    float lx = pb[0], ly = pb[1], lz = pb[2];

    for (int t = 0; t < MM; ++t) {
        // record current sample in LDS (no global traffic inside the loop)
        if (tid == 0) {
            emitP[t] = make_float4(lx, ly, lz, 0.0f);
            emitI[t] = last;
        }

        float nx = -lx, ny = -ly, nz = -lz;
        f32x2 nx2; nx2.x = nx; nx2.y = nx;
        f32x2 ny2; ny2.x = ny; ny2.y = ny;
        f32x2 nz2; nz2.x = nz; nz2.y = nz;

#pragma unroll
        for (int j = 0; j < 8; ++j) {
            f32x2 dx = pk_add(X[j], nx2);
            f32x2 dy = pk_add(Y[j], ny2);
            f32x2 dz = pk_add(Z[j], nz2);
            f32x2 xx = pk_mul(dx, dx);
            f32x2 yy = pk_mul(dy, dy);
            f32x2 zz = pk_mul(dz, dz);
            f32x2 s  = pk_add(pk_add(xx, yy), zz);
            D[j].x = fminf(D[j].x, s.x);
            D[j].y = fminf(D[j].y, s.y);
        }
        f32x2 m0 = pkmax(pkmax(D[0], D[1]), pkmax(D[2], D[3]));
        f32x2 m1 = pkmax(pkmax(D[4], D[5]), pkmax(D[6], D[7]));
        f32x2 mm = pkmax(m0, m1);
        float bv = fmaxf(mm.x, mm.y);

        // local first-argmax recovery (fmax selection is bit-exact)
        int k0 = (D[0].x == bv) ? 0  : ((D[0].y == bv) ? 1  : 16);
        int k1 = (D[1].x == bv) ? 2  : ((D[1].y == bv) ? 3  : 16);
        int k2 = (D[2].x == bv) ? 4  : ((D[2].y == bv) ? 5  : 16);
        int k3 = (D[3].x == bv) ? 6  : ((D[3].y == bv) ? 7  : 16);
        int k4 = (D[4].x == bv) ? 8  : ((D[4].y == bv) ? 9  : 16);
        int k5 = (D[5].x == bv) ? 10 : ((D[5].y == bv) ? 11 : 16);
        int k6 = (D[6].x == bv) ? 12 : ((D[6].y == bv) ? 13 : 16);
        int k7 = (D[7].x == bv) ? 14 : ((D[7].y == bv) ? 15 : 16);
        k0 = min(k0, k4); k1 = min(k1, k5); k2 = min(k2, k6); k3 = min(k3, k7);
        k0 = min(k0, k2); k1 = min(k1, k3);
        int kmin = min(k0, k1);
        int p_cand = tid * 16 + kmin;

        // speculative gather of candidate coords (latency hides under the
        // DPP chain / ballot below; only the winner lane's values are used)
        float sx = posLx[p_cand];
        float sy = posLy[p_cand];
        float sz = posLz[p_cand];

        // VALU-speed wave max-reduce: row_shr 1/2/4/8, row_bcast 15/31
        float r = bv;
        r = dppmax<0x111>(r);
        r = dppmax<0x112>(r);
        r = dppmax<0x114>(r);
        r = dppmax<0x118>(r);
        r = dppmax<0x142>(r);
        r = dppmax<0x143>(r);
        float wmax = __int_as_float(__builtin_amdgcn_readlane(__float_as_int(r), 63));

        // first-occurrence winner within wave (lane order == index order)
        unsigned long long msk = __ballot(bv == wmax);
        int wl = __ffsll((long long)msk) - 1;

        const int p_ = t & 1;
        if (lane == wl) {
            slotP[p_][wv] = make_float4(sx, sy, sz, bv);
            slotI[p_][wv] = p_cand;
        }
        __syncthreads();   // drains only LDS: no global ops pending

        // merge 4 slots (coords ride along; 3 dependent lex-selects)
        float4 e0 = slotP[p_][0], e1 = slotP[p_][1];
        float4 e2 = slotP[p_][2], e3 = slotP[p_][3];
        int    i0 = slotI[p_][0], i1 = slotI[p_][1];
        int    i2 = slotI[p_][2], i3 = slotI[p_][3];

        float cv = e0.w; int ci = i0;
        float cx = e0.x, cy = e0.y, cz = e0.z;
        {
            bool bt = (e1.w > cv) || (e1.w == cv && i1 < ci);
            cv = bt ? e1.w : cv; ci = bt ? i1 : ci;
            cx = bt ? e1.x : cx; cy = bt ? e1.y : cy; cz = bt ? e1.z : cz;
        }
        {
            bool bt = (e2.w > cv) || (e2.w == cv && i2 < ci);
            cv = bt ? e2.w : cv; ci = bt ? i2 : ci;
            cx = bt ? e2.x : cx; cy = bt ? e2.y : cy; cz = bt ? e2.z : cz;
        }
        {
            bool bt = (e3.w > cv) || (e3.w == cv && i3 < ci);
            cv = bt ? e3.w : cv; ci = bt ? i3 : ci;
            cx = bt ? e3.x : cx; cy = bt ? e3.y : cy; cz = bt ? e3.z : cz;
        }
        last = ci; lx = cx; ly = cy; lz = cz;
    }

    __syncthreads();
    // flush buffered samples to global once
    for (int u = tid; u < MM; u += 256) {
        float4 rec = emitP[u];
        int    id  = emitI[u];
        int base = b * MM + u;
        idx_ws[base]  = id;
        out_idx[base] = (float)id;
        out_pos_s[base * 3 + 0] = rec.x;
        out_pos_s[base * 3 + 1] = rec.y;
        out_pos_s[base * 3 + 2] = rec.z;
    }
}

// ---------------------------------------------------------------------------
// Kernel 2: radius search + exact K-smallest selection. One wave per center.
// ---------------------------------------------------------------------------
__global__ __launch_bounds__(256) void radius_kernel(
    const float* __restrict__ pos,
    const float* __restrict__ pos_s,
    int* __restrict__ nbr_ws, int* __restrict__ nvalid_ws)
{
    __shared__ float d2L[4][CAP];
    __shared__ int   idL[4][CAP];
    __shared__ int   cntL[4];

    const int wv = threadIdx.x >> 6, lane = threadIdx.x & 63;
    const int c = blockIdx.x * 4 + wv;
    const int b = c >> 10;
    const float RSQ = 0.0225f;

    if (lane == 0) cntL[wv] = 0;

    float cx = pos_s[c * 3 + 0];
    float cy = pos_s[c * 3 + 1];
    float cz = pos_s[c * 3 + 2];
    const float* pb = pos + (size_t)b * NN * 3;

    for (int it = 0; it < NN / 64; ++it) {
        int p = it * 64 + lane;
        float dx = __fsub_rn(cx, pb[p * 3 + 0]);
        float dy = __fsub_rn(cy, pb[p * 3 + 1]);
        float dz = __fsub_rn(cz, pb[p * 3 + 2]);
        float d2 = __fadd_rn(__fadd_rn(__fmul_rn(dx, dx), __fmul_rn(dy, dy)),
                             __fmul_rn(dz, dz));
        if (d2 <= RSQ) {
            int slot = atomicAdd(&cntL[wv], 1);
            if (slot < CAP) { d2L[wv][slot] = d2; idL[wv][slot] = p; }
        }
    }
    int n = cntL[wv];
    if (n > CAP) n = CAP;

    if (n <= KNB) {
        if (lane == 0) nvalid_ws[c] = n;
        if (lane < n) nbr_ws[c * KNB + lane] = idL[wv][lane];
    } else {
        if (lane == 0) nvalid_ws[c] = KNB;
        for (int a = lane; a < n; a += 64) {
            float da = d2L[wv][a]; int ia = idL[wv][a];
            int r = 0;
            for (int jj = 0; jj < n; ++jj) {
                float dj = d2L[wv][jj]; int ij = idL[wv][jj];
                r += (dj < da || (dj == da && ij < ia)) ? 1 : 0;
            }
            if (r < KNB) nbr_ws[c * KNB + r] = ia;
        }
    }
}

// ---------------------------------------------------------------------------
// Kernel 3: message build -> 68x68 MLP x2 -> masked max-agg -> 68x128 matvec.
// ---------------------------------------------------------------------------
__device__ __forceinline__ float angle3(float ax, float ay, float az,
                                        float bx, float by, float bz)
{
    float cx = ay * bz - az * by;
    float cy = az * bx - ax * bz;
    float cz = ax * by - ay * bx;
    float cn = sqrtf(cx * cx + cy * cy + cz * cz);
    float dt = ax * bx + ay * by + az * bz;
    return atan2f(cn, dt);
}

__device__ __forceinline__ float4 fma4(float m, float4 w, float4 a)
{
    a.x = fmaf(m, w.x, a.x);
    a.y = fmaf(m, w.y, a.y);
    a.z = fmaf(m, w.z, a.z);
    a.w = fmaf(m, w.w, a.w);
    return a;
}

__device__ __forceinline__ void layer_pass(const float* __restrict__ inL,
                                           const float* __restrict__ Ws,
                                           const float* __restrict__ bs,
                                           float* __restrict__ outL, int t)
{
    const int e = t & 63, wvi = t >> 6;
    const bool has5 = (wvi == 0);
    const int j0 = wvi * 4, j1 = (wvi + 4) * 4, j2 = (wvi + 8) * 4,
              j3 = (wvi + 12) * 4, j4 = 64;

    float4 a0 = *reinterpret_cast<const float4*>(bs + j0);
    float4 a1 = *reinterpret_cast<const float4*>(bs + j1);
    float4 a2 = *reinterpret_cast<const float4*>(bs + j2);
    float4 a3 = *reinterpret_cast<const float4*>(bs + j3);
    float4 a4 = has5 ? *reinterpret_cast<const float4*>(bs + j4)
                     : make_float4(0.f, 0.f, 0.f, 0.f);

    const float* row = inL + e * 69;
#pragma unroll 4
    for (int i = 0; i < DIM; ++i) {
        float m = row[i];
        const float* wr = Ws + i * DIM;
        a0 = fma4(m, *reinterpret_cast<const float4*>(wr + j0), a0);
        a1 = fma4(m, *reinterpret_cast<const float4*>(wr + j1), a1);
        a2 = fma4(m, *reinterpret_cast<const float4*>(wr + j2), a2);
        a3 = fma4(m, *reinterpret_cast<const float4*>(wr + j3), a3);
        if (has5) a4 = fma4(m, *reinterpret_cast<const float4*>(wr + j4), a4);
    }

    float* orow = outL + e * 69;
    orow[j0 + 0] = fmaxf(a0.x, 0.f); orow[j0 + 1] = fmaxf(a0.y, 0.f);
    orow[j0 + 2] = fmaxf(a0.z, 0.f); orow[j0 + 3] = fmaxf(a0.w, 0.f);
    orow[j1 + 0] = fmaxf(a1.x, 0.f); orow[j1 + 1] = fmaxf(a1.y, 0.f);
    orow[j1 + 2] = fmaxf(a1.z, 0.f); orow[j1 + 3] = fmaxf(a1.w, 0.f);
    orow[j2 + 0] = fmaxf(a2.x, 0.f); orow[j2 + 1] = fmaxf(a2.y, 0.f);
    orow[j2 + 2] = fmaxf(a2.z, 0.f); orow[j2 + 3] = fmaxf(a2.w, 0.f);
    orow[j3 + 0] = fmaxf(a3.x, 0.f); orow[j3 + 1] = fmaxf(a3.y, 0.f);
    orow[j3 + 2] = fmaxf(a3.z, 0.f); orow[j3 + 3] = fmaxf(a3.w, 0.f);
    if (has5) {
        orow[64] = fmaxf(a4.x, 0.f); orow[65] = fmaxf(a4.y, 0.f);
        orow[66] = fmaxf(a4.z, 0.f); orow[67] = fmaxf(a4.w, 0.f);
    }
}

__global__ __launch_bounds__(256) void mlp_kernel(
    const float* __restrict__ x, const float* __restrict__ pos,
    const float* __restrict__ norm,
    const float* __restrict__ W1, const float* __restrict__ b1,
    const float* __restrict__ W2, const float* __restrict__ b2,
    const float* __restrict__ W3, const float* __restrict__ b3,
    const int* __restrict__ idx_ws, const float* __restrict__ pos_s,
    const int* __restrict__ nbr_ws, const int* __restrict__ nvalid_ws,
    float* __restrict__ out)
{
    __shared__ alignas(16) float W1s[DIM * DIM];
    __shared__ alignas(16) float W2s[DIM * DIM];
    __shared__ alignas(16) float b1s[DIM];
    __shared__ alignas(16) float b2s[DIM];
    __shared__ float msgL[64 * 69];
    __shared__ float h1L[64 * 69];
    __shared__ float aggL[2 * DIM];
    __shared__ int   nvL[2], jLs[64];

    const int t = threadIdx.x;
    const int cg0 = blockIdx.x * 2;

    for (int u = t; u < DIM * DIM; u += 256) { W1s[u] = W1[u]; W2s[u] = W2[u]; }
    if (t < DIM) { b1s[t] = b1[t]; b2s[t] = b2[t]; }
    if (t < 2) nvL[t] = min(nvalid_ws[cg0 + t], KNB);
    __syncthreads();

    const int e = t & 63, fc = t >> 6;
    const int lc = e >> 5, slot = e & 31;
    const int c = cg0 + lc;
    const int b = c >> 10;

    if (fc == 0) {
        int nv = nvL[lc];
        jLs[e] = (slot < nv) ? nbr_ws[c * KNB + slot] : 0;
    }
    __syncthreads();

    const int j = jLs[e];
    {
        const float* xj = x + ((size_t)b * NN + j) * NIN + fc * 16;
#pragma unroll
        for (int r = 0; r < 4; ++r) {
            float4 v = *reinterpret_cast<const float4*>(xj + r * 4);
            msgL[e * 69 + fc * 16 + r * 4 + 0] = v.x;
            msgL[e * 69 + fc * 16 + r * 4 + 1] = v.y;
            msgL[e * 69 + fc * 16 + r * 4 + 2] = v.z;
            msgL[e * 69 + fc * 16 + r * 4 + 3] = v.w;
        }
    }
    if (fc == 0) {
        float pix = pos_s[c * 3 + 0];
        float piy = pos_s[c * 3 + 1];
        float piz = pos_s[c * 3 + 2];
        int ic = idx_ws[c];
        const float* pj_ = pos  + ((size_t)b * NN + j) * 3;
        const float* nj_ = norm + ((size_t)b * NN + j) * 3;
        const float* ni_ = norm + ((size_t)b * NN + ic) * 3;
        float dx = pj_[0] - pix, dy = pj_[1] - piy, dz = pj_[2] - piz;
        float nix = ni_[0], niy = ni_[1], niz = ni_[2];
        float njx = nj_[0], njy = nj_[1], njz = nj_[2];
        msgL[e * 69 + 64] = sqrtf(dx * dx + dy * dy + dz * dz);
        msgL[e * 69 + 65] = angle3(nix, niy, niz, dx, dy, dz);
        msgL[e * 69 + 66] = angle3(njx, njy, njz, dx, dy, dz);
        msgL[e * 69 + 67] = angle3(nix, niy, niz, njx, njy, njz);
    }
    __syncthreads();

    layer_pass(msgL, W1s, b1s, h1L, t);
    __syncthreads();
    layer_pass(h1L, W2s, b2s, msgL, t);
    __syncthreads();

    if (t < 2 * DIM) {
        int cc = t / DIM, jf = t % DIM;
        int nv = nvL[cc];
        float v = -INFINITY;
        for (int s = 0; s < nv; ++s)
            v = fmaxf(v, msgL[(cc * 32 + s) * 69 + jf]);
        aggL[cc * DIM + jf] = v;
    }
    __syncthreads();

    {
        int cc = t >> 7, o = t & 127;
        int cgl = cg0 + cc;
        float acc = b3[o];
#pragma unroll 4
        for (int i = 0; i < DIM; ++i)
            acc = fmaf(aggL[cc * DIM + i], W3[i * NOUTF + o], acc);
        out[(size_t)cgl * NOUTF + o] = fmaxf(acc, 0.0f);
    }
}

// ---------------------------------------------------------------------------
extern "C" void kernel_launch(void* const* d_in, const int* in_sizes, int n_in,
                              void* d_out, int out_size, void* d_ws, size_t ws_size,
                              hipStream_t stream)
{
    const float* x    = (const float*)d_in[0];
    const float* pos  = (const float*)d_in[1];
    const float* norm = (const float*)d_in[2];
    const float* W1 = (const float*)d_in[4];
    const float* b1 = (const float*)d_in[5];
    const float* W2 = (const float*)d_in[6];
    const float* b2 = (const float*)d_in[7];
    const float* W3 = (const float*)d_in[8];
    const float* b3 = (const float*)d_in[9];

    float* out       = (float*)d_out;
    float* out_pos_s = out + (size_t)BB * MM * NOUTF;
    float* out_idx   = out_pos_s + (size_t)BB * MM * 3;

    char* ws = (char*)d_ws;
    int*   idx_ws    = (int*)ws;
    int*   nbr_ws    = (int*)(ws + 131072);
    int*   nvalid_ws = (int*)(ws + 131072 + (size_t)BB * MM * KNB * 4);

    fps_kernel<<<dim3(BB), dim3(256), 0, stream>>>(pos, idx_ws,
                                                   out_pos_s, out_idx);
    radius_kernel<<<dim3((BB * MM) / 4), dim3(256), 0, stream>>>(pos, out_pos_s,
                                                                 nbr_ws, nvalid_ws);
    mlp_kernel<<<dim3((BB * MM) / 2), dim3(256), 0, stream>>>(
        x, pos, norm, W1, b1, W2, b2, W3, b3,
        idx_ws, out_pos_s, nbr_ws, nvalid_ws, out);
}

// Round 13
// 1020.626 us; speedup vs baseline: 1.0995x; 1.0995x over previous
//
#include <hip/hip_runtime.h>
#include <hip/hip_bf16.h>
#include <math.h>

#define BB 8
#define NN 4096
#define NIN 64
#define NOUTF 128
#define KNB 32
#define MM 1024
#define DIM 68
#define CAP 320

typedef float f32x2 __attribute__((ext_vector_type(2)));

__device__ __forceinline__ f32x2 pk_add(f32x2 a, f32x2 b)
{
    f32x2 d;
    asm("v_pk_add_f32 %0, %1, %2" : "=v"(d) : "v"(a), "v"(b));
    return d;
}
__device__ __forceinline__ f32x2 pk_mul(f32x2 a, f32x2 b)
{
    f32x2 d;
    asm("v_pk_mul_f32 %0, %1, %2" : "=v"(d) : "v"(a), "v"(b));
    return d;
}

__device__ __forceinline__ f32x2 pkmax(f32x2 a, f32x2 b)
{
    f32x2 r; r.x = fmaxf(a.x, b.x); r.y = fmaxf(a.y, b.y); return r;
}

template <int CTRL>
__device__ __forceinline__ float dppmax(float v)
{
    int m = __builtin_amdgcn_update_dpp(__float_as_int(v), __float_as_int(v),
                                        CTRL, 0xF, 0xF, false);
    return fmaxf(v, __int_as_float(m));
}

// ---------------------------------------------------------------------------
// Kernel 1: farthest point sampling — EXACT R11 winner (663 us): 256 thr =
// 4 waves, 16 pts/thread, pk-asm scan, max-only + DPP wave-max + ballot,
// slim f32x2 {val,idx} slot merge, post-merge posL broadcast read,
// LDS-buffered emit (no global stores in loop), unroll 2.
// Exact-match: contract off, (dx²+dy²)+dz² order, first-occurrence argmax.
// ---------------------------------------------------------------------------
__global__ __launch_bounds__(256) void fps_kernel(
    const float* __restrict__ pos,
    int* __restrict__ idx_ws,
    float* __restrict__ out_pos_s, float* __restrict__ out_idx)
{
#pragma clang fp contract(off)
    __shared__ float4 posL[NN];      // 64 KiB coords for winner broadcast
    __shared__ f32x2  slot[2][4];    // {val, idx-as-bits} per wave, dbuf
    __shared__ float4 emitP[MM];     // 16 KiB sample coords
    __shared__ int    emitI[MM];     // 4 KiB sample indices

    const int b    = blockIdx.x;
    const int tid  = threadIdx.x;
    const int wv   = tid >> 6;
    const int lane = tid & 63;
    const float* pb = pos + (size_t)b * NN * 3;

    f32x2 X[8], Y[8], Z[8], D[8];
#pragma unroll
    for (int j = 0; j < 8; ++j) {
        int pA = tid * 16 + 2 * j;
        X[j].x = pb[pA * 3 + 0]; X[j].y = pb[pA * 3 + 3];
        Y[j].x = pb[pA * 3 + 1]; Y[j].y = pb[pA * 3 + 4];
        Z[j].x = pb[pA * 3 + 2]; Z[j].y = pb[pA * 3 + 5];
        D[j].x = INFINITY;       D[j].y = INFINITY;
    }
#pragma unroll
    for (int j = 0; j < 16; ++j) {
        int p2 = tid + 256 * j;
        posL[p2] = make_float4(pb[p2 * 3 + 0], pb[p2 * 3 + 1],
                               pb[p2 * 3 + 2], 0.0f);
    }
    __syncthreads();

    int   last = 0;
    float lx = pb[0], ly = pb[1], lz = pb[2];

#pragma unroll 2
    for (int t = 0; t < MM; ++t) {
        if (tid == 0) {
            emitP[t] = make_float4(lx, ly, lz, 0.0f);
            emitI[t] = last;
        }

        float nx = -lx, ny = -ly, nz = -lz;
        f32x2 nx2; nx2.x = nx; nx2.y = nx;
        f32x2 ny2; ny2.x = ny; ny2.y = ny;
        f32x2 nz2; nz2.x = nz; nz2.y = nz;

#pragma unroll
        for (int j = 0; j < 8; ++j) {
            f32x2 dx = pk_add(X[j], nx2);
            f32x2 dy = pk_add(Y[j], ny2);
            f32x2 dz = pk_add(Z[j], nz2);
            f32x2 xx = pk_mul(dx, dx);
            f32x2 yy = pk_mul(dy, dy);
            f32x2 zz = pk_mul(dz, dz);
            f32x2 s  = pk_add(pk_add(xx, yy), zz);
            D[j].x = fminf(D[j].x, s.x);
            D[j].y = fminf(D[j].y, s.y);
        }
        f32x2 m0 = pkmax(pkmax(D[0], D[1]), pkmax(D[2], D[3]));
        f32x2 m1 = pkmax(pkmax(D[4], D[5]), pkmax(D[6], D[7]));
        f32x2 mm = pkmax(m0, m1);
        float bv = fmaxf(mm.x, mm.y);

        int k0 = (D[0].x == bv) ? 0  : ((D[0].y == bv) ? 1  : 16);
        int k1 = (D[1].x == bv) ? 2  : ((D[1].y == bv) ? 3  : 16);
        int k2 = (D[2].x == bv) ? 4  : ((D[2].y == bv) ? 5  : 16);
        int k3 = (D[3].x == bv) ? 6  : ((D[3].y == bv) ? 7  : 16);
        int k4 = (D[4].x == bv) ? 8  : ((D[4].y == bv) ? 9  : 16);
        int k5 = (D[5].x == bv) ? 10 : ((D[5].y == bv) ? 11 : 16);
        int k6 = (D[6].x == bv) ? 12 : ((D[6].y == bv) ? 13 : 16);
        int k7 = (D[7].x == bv) ? 14 : ((D[7].y == bv) ? 15 : 16);
        k0 = min(k0, k4); k1 = min(k1, k5); k2 = min(k2, k6); k3 = min(k3, k7);
        k0 = min(k0, k2); k1 = min(k1, k3);
        int kmin = min(k0, k1);
        int p_cand = tid * 16 + kmin;

        float r = bv;
        r = dppmax<0x111>(r);
        r = dppmax<0x112>(r);
        r = dppmax<0x114>(r);
        r = dppmax<0x118>(r);
        r = dppmax<0x142>(r);
        r = dppmax<0x143>(r);
        float wmax = __int_as_float(__builtin_amdgcn_readlane(__float_as_int(r), 63));

        unsigned long long msk = __ballot(bv == wmax);
        int wl = __ffsll((long long)msk) - 1;
        int pwin_wave = __builtin_amdgcn_readlane(p_cand, wl);

        const int p_ = t & 1;
        if (lane == 0) {
            f32x2 sv; sv.x = wmax; sv.y = __int_as_float(pwin_wave);
            slot[p_][wv] = sv;
        }
        __syncthreads();

        f32x2 s0 = slot[p_][0], s1 = slot[p_][1];
        f32x2 s2 = slot[p_][2], s3 = slot[p_][3];
        float cv = s0.x; int ci = __float_as_int(s0.y);
        {
            int i1 = __float_as_int(s1.y);
            bool bt = (s1.x > cv) || (s1.x == cv && i1 < ci);
            cv = bt ? s1.x : cv; ci = bt ? i1 : ci;
        }
        {
            int i2 = __float_as_int(s2.y);
            bool bt = (s2.x > cv) || (s2.x == cv && i2 < ci);
            cv = bt ? s2.x : cv; ci = bt ? i2 : ci;
        }
        {
            int i3 = __float_as_int(s3.y);
            bool bt = (s3.x > cv) || (s3.x == cv && i3 < ci);
            cv = bt ? s3.x : cv; ci = bt ? i3 : ci;
        }

        float4 cw = posL[ci];
        last = ci; lx = cw.x; ly = cw.y; lz = cw.z;
    }

    __syncthreads();
    for (int u = tid; u < MM; u += 256) {
        float4 rec = emitP[u];
        int    id  = emitI[u];
        int base = b * MM + u;
        idx_ws[base]  = id;
        out_idx[base] = (float)id;
        out_pos_s[base * 3 + 0] = rec.x;
        out_pos_s[base * 3 + 1] = rec.y;
        out_pos_s[base * 3 + 2] = rec.z;
    }
}

// ---------------------------------------------------------------------------
// Kernel 2 (FUSED radius + mlp). Block = 2 centers, 256 threads.
// Phase A: stage W1/W2 into LDS (loads overlap radius) + radius search with
// 128 threads per center -> LDS candidate list -> exact (d2,idx)-rank
// selection (neighbor SET deterministic; order irrelevant: max-agg is
// order-invariant). Phase B: message build -> 68x68 MLP x2 -> masked
// max-agg -> 68x128 matvec. No nbr/nvalid global round-trip.
// ---------------------------------------------------------------------------
__device__ __forceinline__ float angle3(float ax, float ay, float az,
                                        float bx, float by, float bz)
{
    float cx = ay * bz - az * by;
    float cy = az * bx - ax * bz;
    float cz = ax * by - ay * bx;
    float cn = sqrtf(cx * cx + cy * cy + cz * cz);
    float dt = ax * bx + ay * by + az * bz;
    return atan2f(cn, dt);
}

__device__ __forceinline__ float4 fma4(float m, float4 w, float4 a)
{
    a.x = fmaf(m, w.x, a.x);
    a.y = fmaf(m, w.y, a.y);
    a.z = fmaf(m, w.z, a.z);
    a.w = fmaf(m, w.w, a.w);
    return a;
}

__device__ __forceinline__ void layer_pass(const float* __restrict__ inL,
                                           const float* __restrict__ Ws,
                                           const float* __restrict__ bs,
                                           float* __restrict__ outL, int t)
{
    const int e = t & 63, wvi = t >> 6;
    const bool has5 = (wvi == 0);
    const int j0 = wvi * 4, j1 = (wvi + 4) * 4, j2 = (wvi + 8) * 4,
              j3 = (wvi + 12) * 4, j4 = 64;

    float4 a0 = *reinterpret_cast<const float4*>(bs + j0);
    float4 a1 = *reinterpret_cast<const float4*>(bs + j1);
    float4 a2 = *reinterpret_cast<const float4*>(bs + j2);
    float4 a3 = *reinterpret_cast<const float4*>(bs + j3);
    float4 a4 = has5 ? *reinterpret_cast<const float4*>(bs + j4)
                     : make_float4(0.f, 0.f, 0.f, 0.f);

    const float* row = inL + e * 69;
#pragma unroll 4
    for (int i = 0; i < DIM; ++i) {
        float m = row[i];
        const float* wr = Ws + i * DIM;
        a0 = fma4(m, *reinterpret_cast<const float4*>(wr + j0), a0);
        a1 = fma4(m, *reinterpret_cast<const float4*>(wr + j1), a1);
        a2 = fma4(m, *reinterpret_cast<const float4*>(wr + j2), a2);
        a3 = fma4(m, *reinterpret_cast<const float4*>(wr + j3), a3);
        if (has5) a4 = fma4(m, *reinterpret_cast<const float4*>(wr + j4), a4);
    }

    float* orow = outL + e * 69;
    orow[j0 + 0] = fmaxf(a0.x, 0.f); orow[j0 + 1] = fmaxf(a0.y, 0.f);
    orow[j0 + 2] = fmaxf(a0.z, 0.f); orow[j0 + 3] = fmaxf(a0.w, 0.f);
    orow[j1 + 0] = fmaxf(a1.x, 0.f); orow[j1 + 1] = fmaxf(a1.y, 0.f);
    orow[j1 + 2] = fmaxf(a1.z, 0.f); orow[j1 + 3] = fmaxf(a1.w, 0.f);
    orow[j2 + 0] = fmaxf(a2.x, 0.f); orow[j2 + 1] = fmaxf(a2.y, 0.f);
    orow[j2 + 2] = fmaxf(a2.z, 0.f); orow[j2 + 3] = fmaxf(a2.w, 0.f);
    orow[j3 + 0] = fmaxf(a3.x, 0.f); orow[j3 + 1] = fmaxf(a3.y, 0.f);
    orow[j3 + 2] = fmaxf(a3.z, 0.f); orow[j3 + 3] = fmaxf(a3.w, 0.f);
    if (has5) {
        orow[64] = fmaxf(a4.x, 0.f); orow[65] = fmaxf(a4.y, 0.f);
        orow[66] = fmaxf(a4.z, 0.f); orow[67] = fmaxf(a4.w, 0.f);
    }
}

__global__ __launch_bounds__(256) void fused_kernel(
    const float* __restrict__ x, const float* __restrict__ pos,
    const float* __restrict__ norm,
    const float* __restrict__ W1, const float* __restrict__ b1,
    const float* __restrict__ W2, const float* __restrict__ b2,
    const float* __restrict__ W3, const float* __restrict__ b3,
    const int* __restrict__ idx_ws, const float* __restrict__ pos_s,
    float* __restrict__ out)
{
    __shared__ alignas(16) float W1s[DIM * DIM];
    __shared__ alignas(16) float W2s[DIM * DIM];
    __shared__ alignas(16) float b1s[DIM];
    __shared__ alignas(16) float b2s[DIM];
    __shared__ float msgL[64 * 69];
    __shared__ float h1L[64 * 69];
    __shared__ float aggL[2 * DIM];
    __shared__ float d2L[2][CAP];
    __shared__ int   idL[2][CAP];
    __shared__ int   cntL[2];
    __shared__ int   nbrL[2][KNB];
    __shared__ int   nvL[2];

    const int t = threadIdx.x;
    const int cg0 = blockIdx.x * 2;

    // ---- Phase A: weight staging (loads in flight) + radius init ----
    for (int u = t; u < DIM * DIM; u += 256) { W1s[u] = W1[u]; W2s[u] = W2[u]; }
    if (t < DIM) { b1s[t] = b1[t]; b2s[t] = b2[t]; }
    if (t < 2) cntL[t] = 0;
    __syncthreads();

    {
        const int half  = t >> 7;       // 0/1: local center
        const int hlane = t & 127;
        const int c  = cg0 + half;
        const int bb = c >> 10;
        const float RSQ = 0.0225f;

        float cx = pos_s[c * 3 + 0];
        float cy = pos_s[c * 3 + 1];
        float cz = pos_s[c * 3 + 2];
        const float* pb = pos + (size_t)bb * NN * 3;

        for (int it = 0; it < NN / 128; ++it) {
            int p = it * 128 + hlane;
            float dx = __fsub_rn(cx, pb[p * 3 + 0]);
            float dy = __fsub_rn(cy, pb[p * 3 + 1]);
            float dz = __fsub_rn(cz, pb[p * 3 + 2]);
            float d2 = __fadd_rn(__fadd_rn(__fmul_rn(dx, dx), __fmul_rn(dy, dy)),
                                 __fmul_rn(dz, dz));
            if (d2 <= RSQ) {
                int s = atomicAdd(&cntL[half], 1);
                if (s < CAP) { d2L[half][s] = d2; idL[half][s] = p; }
            }
        }
        __syncthreads();

        int n = cntL[half];
        if (n > CAP) n = CAP;
        if (hlane == 0) nvL[half] = min(n, KNB);

        if (n <= KNB) {
            if (hlane < n) nbrL[half][hlane] = idL[half][hlane];
        } else {
            for (int a = hlane; a < n; a += 128) {
                float da = d2L[half][a]; int ia = idL[half][a];
                int r = 0;
                for (int jj = 0; jj < n; ++jj) {
                    float dj = d2L[half][jj]; int ij = idL[half][jj];
                    r += (dj < da || (dj == da && ij < ia)) ? 1 : 0;
                }
                if (r < KNB) nbrL[half][r] = ia;
            }
        }
    }
    __syncthreads();

    // ---- Phase B: mlp ----
    const int e = t & 63, fc = t >> 6;
    const int lc = e >> 5, slot = e & 31;
    const int c = cg0 + lc;
    const int b = c >> 10;

    const int nv = nvL[lc];
    const int j  = (slot < nv) ? nbrL[lc][slot] : 0;

    {
        const float* xj = x + ((size_t)b * NN + j) * NIN + fc * 16;
#pragma unroll
        for (int r = 0; r < 4; ++r) {
            float4 v = *reinterpret_cast<const float4*>(xj + r * 4);
            msgL[e * 69 + fc * 16 + r * 4 + 0] = v.x;
            msgL[e * 69 + fc * 16 + r * 4 + 1] = v.y;
            msgL[e * 69 + fc * 16 + r * 4 + 2] = v.z;
            msgL[e * 69 + fc * 16 + r * 4 + 3] = v.w;
        }
    }
    if (fc == 0) {
        float pix = pos_s[c * 3 + 0];
        float piy = pos_s[c * 3 + 1];
        float piz = pos_s[c * 3 + 2];
        int ic = idx_ws[c];
        const float* pj_ = pos  + ((size_t)b * NN + j) * 3;
        const float* nj_ = norm + ((size_t)b * NN + j) * 3;
        const float* ni_ = norm + ((size_t)b * NN + ic) * 3;
        float dx = pj_[0] - pix, dy = pj_[1] - piy, dz = pj_[2] - piz;
        float nix = ni_[0], niy = ni_[1], niz = ni_[2];
        float njx = nj_[0], njy = nj_[1], njz = nj_[2];
        msgL[e * 69 + 64] = sqrtf(dx * dx + dy * dy + dz * dz);
        msgL[e * 69 + 65] = angle3(nix, niy, niz, dx, dy, dz);
        msgL[e * 69 + 66] = angle3(njx, njy, njz, dx, dy, dz);
        msgL[e * 69 + 67] = angle3(nix, niy, niz, njx, njy, njz);
    }
    __syncthreads();

    layer_pass(msgL, W1s, b1s, h1L, t);
    __syncthreads();
    layer_pass(h1L, W2s, b2s, msgL, t);
    __syncthreads();

    if (t < 2 * DIM) {
        int cc = t / DIM, jf = t % DIM;
        int nvv = nvL[cc];
        float v = -INFINITY;
        for (int s = 0; s < nvv; ++s)
            v = fmaxf(v, msgL[(cc * 32 + s) * 69 + jf]);
        aggL[cc * DIM + jf] = v;
    }
    __syncthreads();

    {
        int cc = t >> 7, o = t & 127;
        int cgl = cg0 + cc;
        float acc = b3[o];
#pragma unroll 4
        for (int i = 0; i < DIM; ++i)
            acc = fmaf(aggL[cc * DIM + i], W3[i * NOUTF + o], acc);
        out[(size_t)cgl * NOUTF + o] = fmaxf(acc, 0.0f);
    }
}

// ---------------------------------------------------------------------------
extern "C" void kernel_launch(void* const* d_in, const int* in_sizes, int n_in,
                              void* d_out, int out_size, void* d_ws, size_t ws_size,
                              hipStream_t stream)
{
    const float* x    = (const float*)d_in[0];
    const float* pos  = (const float*)d_in[1];
    const float* norm = (const float*)d_in[2];
    const float* W1 = (const float*)d_in[4];
    const float* b1 = (const float*)d_in[5];
    const float* W2 = (const float*)d_in[6];
    const float* b2 = (const float*)d_in[7];
    const float* W3 = (const float*)d_in[8];
    const float* b3 = (const float*)d_in[9];

    float* out       = (float*)d_out;
    float* out_pos_s = out + (size_t)BB * MM * NOUTF;
    float* out_idx   = out_pos_s + (size_t)BB * MM * 3;

    char* ws = (char*)d_ws;
    int* idx_ws = (int*)ws;

    fps_kernel<<<dim3(BB), dim3(256), 0, stream>>>(pos, idx_ws,
                                                   out_pos_s, out_idx);
    fused_kernel<<<dim3((BB * MM) / 2), dim3(256), 0, stream>>>(
        x, pos, norm, W1, b1, W2, b2, W3, b3,
        idx_ws, out_pos_s, out);
}